// Round 4
// baseline (231.340 us; speedup 1.0000x reference)
//
#include <hip/hip_runtime.h>
#include <hip/hip_cooperative_groups.h>
#include <math.h>

namespace cg = cooperative_groups;

#define N 1024
#define C 81
#define F 1024
#define K 100
#define NC1 80              // C-1 foreground classes
#define MAXC (NC1 * N)      // dense candidate capacity
#define HBASE 0x3D00        // hist bucket base: float bits >>16
#define HSIZE 1024          // covers score in (0.05, 1]: buckets 76..640
#define SELCAP 2048         // LDS select capacity
#define GRID 256            // cooperative grid (1 block/CU)

#define SCORE_THRESH 0.05f
#define NMS_THRESH   0.5f
#define BBOX_CLIP    4.135166556742356f   // log(1000/16)
#define IMG_W1       1215.0f
#define IMG_H1       799.0f

typedef unsigned long long u64;
typedef unsigned int u32;

// ---- decode one (proposal idx, class cl) box — expressions verbatim from the
// absmax==0 kernels so contraction/codegen matches.
__device__ float4 decode_box(const float* __restrict__ pboxes,
                             const float* __restrict__ boxreg, int idx, int cl)
{
    float4 pb = ((const float4*)pboxes)[idx];
    float4 r  = *(const float4*)(boxreg + (size_t)idx * (C * 4) + cl * 4);
    float w  = pb.z - pb.x + 1.0f, h = pb.w - pb.y + 1.0f;
    float cx = pb.x + 0.5f * w,  cy = pb.y + 0.5f * h;
    float dx = r.x / 10.0f, dy = r.y / 10.0f;
    float dw = fminf(r.z / 5.0f, BBOX_CLIP);
    float dh = fminf(r.w / 5.0f, BBOX_CLIP);
    float pcx = dx * w + cx, pcy = dy * h + cy;
    float pw = expf(dw) * w, ph = expf(dh) * h;
    float x1 = pcx - 0.5f * pw,        y1 = pcy - 0.5f * ph;
    float x2 = pcx + 0.5f * pw - 1.0f, y2 = pcy + 0.5f * ph - 1.0f;
    x1 = fminf(fmaxf(x1, 0.0f), IMG_W1);
    y1 = fminf(fmaxf(y1, 0.0f), IMG_H1);
    x2 = fminf(fmaxf(x2, 0.0f), IMG_W1);
    y2 = fminf(fmaxf(y2, 0.0f), IMG_H1);
    return make_float4(x1, y1, x2, y2);
}

// ---------------- single cooperative kernel: A|B|C|D with 3 grid syncs ------
__global__ __launch_bounds__(256) void k_fused(
    const float* __restrict__ logits, const float* __restrict__ boxreg,
    const float* __restrict__ pboxes, const float* __restrict__ feats,
    float* __restrict__ out,
    u64* __restrict__ ckey, float4* __restrict__ cbox, int* __restrict__ corig,
    float2* __restrict__ ms, int* __restrict__ hist, int* __restrict__ counter,
    float* __restrict__ sel_score, int* __restrict__ sel_flat)
{
    cg::grid_group grid = cg::this_grid();
    int t   = threadIdx.x;
    int blk = blockIdx.x;

    // phase-B layout: skey64[N] | sbox[N] | sarea[N] | skeep[N]  (32 KiB)
    // phase-C layout: keys[SELCAP] overlays the front 16 KiB (phases disjoint)
    __shared__ __align__(16) char smem[32768];
    u64*    skey64 = (u64*)smem;
    float4* sbox   = (float4*)(smem + 8192);
    float*  sarea  = (float*)(smem + 24576);
    int*    skeep  = (int*)(smem + 28672);
    __shared__ int scnt[256];
    __shared__ int sbstar, scount;
    __shared__ u64 wk[4];
    __shared__ int wp[4];

    // ============ phase A: per-row softmax stats (bit-exact butterfly) =====
    {
        int gid = blk * 256 + t;
        if (gid < HSIZE) hist[gid] = 0;
        if (gid == 0) *counter = 0;

        int n = blk * 4 + (t >> 6);
        int l = t & 63;
        float v1 = logits[n * C + l];
        float v2 = (l < C - 64) ? logits[n * C + 64 + l] : -INFINITY;
        float m = fmaxf(v1, v2);
        for (int off = 32; off; off >>= 1) m = fmaxf(m, __shfl_xor(m, off));
        float e1 = expf(v1 - m);
        float e2 = (l < C - 64) ? expf(v2 - m) : 0.0f;
        float s = e1 + e2;
        for (int off = 32; off; off >>= 1) s += __shfl_xor(s, off);
        if (l == 0) ms[n] = make_float2(m, s);
    }
    __threadfence();
    grid.sync();

    // ============ phase B: per-class score -> sort -> NMS (blocks 0..79) ===
    if (blk < NC1) {
        int c = blk, cl = c + 1;
        float2 p0 = ms[t],       p1 = ms[t + 256];
        float2 p2 = ms[t + 512], p3 = ms[t + 768];
        float s0 = expf(logits[(t      ) * C + cl] - p0.x) / p0.y;
        float s1 = expf(logits[(t + 256) * C + cl] - p1.x) / p1.y;
        float s2 = expf(logits[(t + 512) * C + cl] - p2.x) / p2.y;
        float s3 = expf(logits[(t + 768) * C + cl] - p3.x) / p3.y;
        int f0 = s0 > SCORE_THRESH, f1 = s1 > SCORE_THRESH;
        int f2 = s2 > SCORE_THRESH, f3 = s3 > SCORE_THRESH;
        int mycount = f0 + f1 + f2 + f3;
        scnt[t] = mycount;
        __syncthreads();
        for (int off = 1; off < 256; off <<= 1) {
            int v = scnt[t];
            int a = (t >= off) ? scnt[t - off] : 0;
            __syncthreads();
            scnt[t] = v + a;
            __syncthreads();
        }
        int base = scnt[t] - mycount;
        int V = scnt[255];
        {
            int pos = base;
            if (f0) skey64[pos++] = ((u64)__float_as_uint(s0) << 32) | (u32)~(u32)(t);
            if (f1) skey64[pos++] = ((u64)__float_as_uint(s1) << 32) | (u32)~(u32)(t + 256);
            if (f2) skey64[pos++] = ((u64)__float_as_uint(s2) << 32) | (u32)~(u32)(t + 512);
            if (f3) skey64[pos++] = ((u64)__float_as_uint(s3) << 32) | (u32)~(u32)(t + 768);
        }
        __syncthreads();

        if (V > 0 && V <= 64) {
            if (t < 64) {
                int lane = t;
                u64 key = (lane < V) ? skey64[lane] : 0ull;
                // descending bitonic over 64 lanes (keys unique; 0-pad sinks)
                for (int k = 2; k <= 64; k <<= 1) {
                    for (int j = k >> 1; j > 0; j >>= 1) {
                        u64 other = __shfl_xor(key, j);
                        bool takeMax = (((lane & j) == 0) == ((lane & k) == 0));
                        bool gt = key > other;
                        key = (takeMax == gt) ? key : other;
                    }
                }
                bool act = key != 0ull;
                float4 b = make_float4(0.f, 0.f, 0.f, 0.f);
                float area = 0.0f;
                if (act) {
                    int idx = (int)(~(u32)(key & 0xffffffffu));
                    b = decode_box(pboxes, boxreg, idx, cl);
                    area = (b.z - b.x + 1.0f) * (b.w - b.y + 1.0f);
                    cbox[c * N + lane]  = b;
                    corig[c * N + lane] = idx;
                }
                int kept = act ? 1 : 0;
                for (int i = 0; i + 1 < V; ++i) {
                    int   ki  = __shfl(kept, i);
                    float bix = __shfl(b.x, i), biy = __shfl(b.y, i);
                    float biz = __shfl(b.z, i), biw = __shfl(b.w, i);
                    float ai  = __shfl(area, i);
                    if (ki && lane > i && kept) {
                        float lx = fmaxf(bix, b.x), ly = fmaxf(biy, b.y);
                        float rx = fminf(biz, b.z), ry = fminf(biw, b.w);
                        float ww = fmaxf(rx - lx + 1.0f, 0.0f);
                        float hh = fmaxf(ry - ly + 1.0f, 0.0f);
                        float inter = ww * hh;
                        float iou = inter / (ai + area - inter);
                        if (iou > NMS_THRESH) kept = 0;
                    }
                }
                if (kept) {
                    int pos = atomicAdd(counter, 1);
                    u32 sb = (u32)(key >> 32);
                    ckey[pos] = ((u64)sb << 32) | (u64)(u32)~(u32)(c * N + lane);
                    atomicAdd(&hist[(int)(sb >> 16) - HBASE], 1);
                }
            }
        } else if (V > 64) {
            // ---------- fallback: LDS bitonic on P = next pow2 ----------
            int P = 128;
            while (P < V) P <<= 1;
            for (int i = V + t; i < P; i += 256) skey64[i] = 0ull;
            __syncthreads();
            for (int k = 2; k <= P; k <<= 1) {
                for (int j = k >> 1; j > 0; j >>= 1) {
                    for (int i = t; i < P; i += 256) {
                        int ixj = i ^ j;
                        if (ixj > i) {
                            u64 a = skey64[i], bb = skey64[ixj];
                            bool desc = ((i & k) == 0);
                            if (desc ? (a < bb) : (a > bb)) { skey64[i] = bb; skey64[ixj] = a; }
                        }
                    }
                    __syncthreads();
                }
            }
            for (int p = t; p < V; p += 256) {
                int idx = (int)(~(u32)(skey64[p] & 0xffffffffu));
                float4 b = decode_box(pboxes, boxreg, idx, cl);
                sbox[p]  = b;
                sarea[p] = (b.z - b.x + 1.0f) * (b.w - b.y + 1.0f);
                skeep[p] = 1;
                cbox[c * N + p]  = b;
                corig[c * N + p] = idx;
            }
            __syncthreads();
            for (int i = 0; i < V; ++i) {
                if (skeep[i]) {
                    float4 bi = sbox[i];
                    float  ai = sarea[i];
                    for (int j = i + 1 + t; j < V; j += 256) {
                        if (skeep[j]) {
                            float4 bj = sbox[j];
                            float lx = fmaxf(bi.x, bj.x), ly = fmaxf(bi.y, bj.y);
                            float rx = fminf(bi.z, bj.z), ry = fminf(bi.w, bj.w);
                            float ww = fmaxf(rx - lx + 1.0f, 0.0f);
                            float hh = fmaxf(ry - ly + 1.0f, 0.0f);
                            float inter = ww * hh;
                            float iou = inter / (ai + sarea[j] - inter);
                            if (iou > NMS_THRESH) skeep[j] = 0;
                        }
                    }
                }
                __syncthreads();
            }
            for (int p = t; p < V; p += 256) {
                if (skeep[p]) {
                    int pos = atomicAdd(counter, 1);
                    u32 sb = (u32)(skey64[p] >> 32);
                    ckey[pos] = ((u64)sb << 32) | (u64)(u32)~(u32)(c * N + p);
                    atomicAdd(&hist[(int)(sb >> 16) - HBASE], 1);
                }
            }
        }
    }
    __threadfence();
    grid.sync();

    // ============ phase C: exact top-K select (block 0, 256 threads) =======
    if (blk == 0) {
        int M = *counter;
        if (t == 0) { sbstar = 0; scount = 0; }

        // two-level suffix scan of 1024-bucket hist: thread t owns buckets
        // 4t..4t+3; same base arithmetic as the proven 1024-thread version.
        int h0 = hist[4 * t], h1 = hist[4 * t + 1];
        int h2 = hist[4 * t + 2], h3 = hist[4 * t + 3];
        int gs = h0 + h1 + h2 + h3;
        scnt[t] = gs;
        __syncthreads();
        for (int off = 1; off < 256; off <<= 1) {
            int v = scnt[t];
            int a = (t + off < 256) ? scnt[t + off] : 0;
            __syncthreads();
            scnt[t] = v + a;
            __syncthreads();
        }
        int above = scnt[t] - gs;            // keys in bucket-groups above t
        int b3 = above, b2 = b3 + h3, b1 = b2 + h2, b0 = b1 + h1;
        if (b0 < K && b0 + h0 >= K) sbstar = 4 * t;
        if (b1 < K && b1 + h1 >= K) sbstar = 4 * t + 1;
        if (b2 < K && b2 + h2 >= K) sbstar = 4 * t + 2;
        if (b3 < K && b3 + h3 >= K) sbstar = 4 * t + 3;
        __syncthreads();
        int bstar = sbstar;

        // compact keys with bucket >= bstar into LDS (overlays phase-B smem)
        u64* keys = (u64*)smem;
        for (int p = t; p < M; p += 256) {
            u64 kk = ckey[p];
            int b = (int)((kk >> 48) & 0xFFFF) - HBASE;
            if (b >= bstar) {
                int pos = atomicAdd(&scount, 1);
                if (pos < SELCAP) keys[pos] = kk;
            }
        }
        __syncthreads();
        int cnt = scount;

        if (cnt > SELCAP) {
            // exact fallback (tie flood): K rounds of argmax over dense ckey
            for (int k = 0; k < K; ++k) {
                u64 key = 0ull; int pos = -1;
                for (int p = t; p < M; p += 256) {
                    u64 kk = ckey[p];
                    if (kk > key) { key = kk; pos = p; }
                }
                for (int off = 32; off; off >>= 1) {
                    u64 ok2 = __shfl_down(key, off);
                    int op  = __shfl_down(pos, off);
                    if (ok2 > key) { key = ok2; pos = op; }
                }
                if ((t & 63) == 0) { wk[t >> 6] = key; wp[t >> 6] = pos; }
                __syncthreads();
                if (t == 0) {
                    for (int w = 1; w < 4; ++w)
                        if (wk[w] > key) { key = wk[w]; pos = wp[w]; }
                    if (key != 0ull) {
                        sel_score[k] = __uint_as_float((u32)(key >> 32));
                        sel_flat[k]  = (int)(~(u32)(key & 0xffffffffu));
                        ckey[pos] = 0ull;
                    } else { sel_score[k] = 0.0f; sel_flat[k] = 0; }
                }
                __syncthreads();
            }
        } else {
            int P = 128;
            while (P < cnt) P <<= 1;
            for (int i = cnt + t; i < P; i += 256) keys[i] = 0ull;
            __syncthreads();
            for (int k = 2; k <= P; k <<= 1) {
                for (int j = k >> 1; j > 0; j >>= 1) {
                    for (int i = t; i < P; i += 256) {
                        int ixj = i ^ j;
                        if (ixj > i) {
                            u64 a = keys[i], b = keys[ixj];
                            bool desc = ((i & k) == 0);
                            if (desc ? (a < b) : (a > b)) { keys[i] = b; keys[ixj] = a; }
                        }
                    }
                    __syncthreads();
                }
            }
            if (t < K) {
                u64 key = keys[t];
                sel_score[t] = __uint_as_float((u32)(key >> 32));
                sel_flat[t]  = (int)(~(u32)(key & 0xffffffffu));
            }
        }
    }
    __threadfence();
    grid.sync();

    // ============ phase D: gather outputs (blocks 0..K-1) ==================
    // out layout: boxes[K*4] | scores[K] | feats[K*F] | labels[K]  (all f32)
    if (blk < K) {
        int k = blk;
        float s = sel_score[k];
        bool ok = s > 0.0f;
        float4 b = make_float4(0.f, 0.f, 0.f, 0.f);
        int label = 0, orig = 0;
        if (ok) {
            int flat = sel_flat[k];        // c*N + rank
            orig  = corig[flat];
            b     = cbox[flat];
            label = (flat >> 10) + 1;      // N = 1024
        }
        if (t == 0) {
            out[k * 4 + 0] = b.x; out[k * 4 + 1] = b.y;
            out[k * 4 + 2] = b.z; out[k * 4 + 3] = b.w;
            out[K * 4 + k] = ok ? s : 0.0f;
            out[K * 4 + K + K * F + k] = (float)label;
        }
        const float4* src = (const float4*)(feats + (size_t)orig * F);
        float4* dst = (float4*)(out + K * 4 + K + (size_t)k * F);
        float4 z = make_float4(0.f, 0.f, 0.f, 0.f);
        if (t < F / 4) dst[t] = ok ? src[t] : z;   // F/4 == 256 == blockDim
    }
}

// ---------------------------------------------------------------------------
extern "C" void kernel_launch(void* const* d_in, const int* in_sizes, int n_in,
                              void* d_out, int out_size, void* d_ws, size_t ws_size,
                              hipStream_t stream)
{
    const float* logits = (const float*)d_in[0];   // [N,C]
    const float* boxreg = (const float*)d_in[1];   // [N,C*4]
    const float* pboxes = (const float*)d_in[2];   // [N,4]
    const float* feats  = (const float*)d_in[3];   // [N,F]
    float* out = (float*)d_out;

    char* ws = (char*)d_ws;
    size_t off = 0;
    auto alloc = [&](size_t bytes) {
        size_t cur = off;
        off = (off + bytes + 255) & ~(size_t)255;
        return cur;
    };
    u64*    ckey      = (u64*)   (ws + alloc(sizeof(u64)    * MAXC));
    float4* cbox      = (float4*)(ws + alloc(sizeof(float4) * NC1 * N));
    int*    corig     = (int*)   (ws + alloc(sizeof(int)    * NC1 * N));
    float2* ms        = (float2*)(ws + alloc(sizeof(float2) * N));
    int*    hist      = (int*)   (ws + alloc(sizeof(int)    * HSIZE));
    int*    counter   = (int*)   (ws + alloc(sizeof(int)));
    float*  sel_score = (float*) (ws + alloc(sizeof(float)  * K));
    int*    sel_flat  = (int*)   (ws + alloc(sizeof(int)    * K));

    void* kargs[] = {
        (void*)&logits, (void*)&boxreg, (void*)&pboxes, (void*)&feats,
        (void*)&out, (void*)&ckey, (void*)&cbox, (void*)&corig,
        (void*)&ms, (void*)&hist, (void*)&counter,
        (void*)&sel_score, (void*)&sel_flat
    };
    hipLaunchCooperativeKernel((const void*)k_fused, dim3(GRID), dim3(256),
                               kargs, 0, stream);
}

// Round 5
// 111.626 us; speedup vs baseline: 2.0725x; 2.0725x over previous
//
#include <hip/hip_runtime.h>
#include <math.h>

#define N 1024
#define C 81
#define F 1024
#define K 100
#define NC1 80              // C-1 foreground classes
#define MAXC (NC1 * N)      // dense candidate capacity
#define HBASE 0x3D00        // hist bucket base: float bits >>16
#define HSIZE 1024          // covers score in (0.05, 1]: buckets 76..640
#define SELCAP 2048         // LDS select capacity

#define SCORE_THRESH 0.05f
#define NMS_THRESH   0.5f
#define BBOX_CLIP    4.135166556742356f   // log(1000/16)
#define IMG_W1       1215.0f
#define IMG_H1       799.0f

typedef unsigned long long u64;
typedef unsigned int u32;

// ---- decode one (proposal idx, class cl) box — expressions verbatim from the
// absmax==0 kernels so contraction/codegen matches.
__device__ float4 decode_box(const float* __restrict__ pboxes,
                             const float* __restrict__ boxreg, int idx, int cl)
{
    float4 pb = ((const float4*)pboxes)[idx];
    float4 r  = *(const float4*)(boxreg + (size_t)idx * (C * 4) + cl * 4);
    float w  = pb.z - pb.x + 1.0f, h = pb.w - pb.y + 1.0f;
    float cx = pb.x + 0.5f * w,  cy = pb.y + 0.5f * h;
    float dx = r.x / 10.0f, dy = r.y / 10.0f;
    float dw = fminf(r.z / 5.0f, BBOX_CLIP);
    float dh = fminf(r.w / 5.0f, BBOX_CLIP);
    float pcx = dx * w + cx, pcy = dy * h + cy;
    float pw = expf(dw) * w, ph = expf(dh) * h;
    float x1 = pcx - 0.5f * pw,        y1 = pcy - 0.5f * ph;
    float x2 = pcx + 0.5f * pw - 1.0f, y2 = pcy + 0.5f * ph - 1.0f;
    x1 = fminf(fmaxf(x1, 0.0f), IMG_W1);
    y1 = fminf(fmaxf(y1, 0.0f), IMG_H1);
    x2 = fminf(fmaxf(x2, 0.0f), IMG_W1);
    y2 = fminf(fmaxf(y2, 0.0f), IMG_H1);
    return make_float4(x1, y1, x2, y2);
}

// ---------------- per-row softmax stats (m, s), computed ONCE ---------------
// one wave per row, bit-exact replica of the original butterfly. Also zeroes
// hist + counter + done (grid covers HSIZE threads). ms[r] = (max, denom).
__global__ __launch_bounds__(256) void k_softmax(
    const float* __restrict__ logits, float2* __restrict__ ms,
    int* __restrict__ hist, int* __restrict__ counter, int* __restrict__ done)
{
    int gid = blockIdx.x * 256 + threadIdx.x;
    if (gid < HSIZE) hist[gid] = 0;
    if (gid == 0) { *counter = 0; *done = 0; }

    int n = blockIdx.x * 4 + (threadIdx.x >> 6);
    int t = threadIdx.x & 63;

    float v1 = logits[n * C + t];
    float v2 = (t < C - 64) ? logits[n * C + 64 + t] : -INFINITY;
    float m = fmaxf(v1, v2);
    for (int off = 32; off; off >>= 1) m = fmaxf(m, __shfl_xor(m, off));
    float e1 = expf(v1 - m);
    float e2 = (t < C - 64) ? expf(v2 - m) : 0.0f;
    float s = e1 + e2;
    for (int off = 32; off; off >>= 1) s += __shfl_xor(s, off);

    if (t == 0) ms[n] = make_float2(m, s);
}

// ---------------- per-class NMS + last-block inline top-K select ------------
// 80 blocks. Class phase is byte-identical logic to the proven round-3
// k_class (restructured return-free). Each block then fences and bumps a
// done-counter; the LAST block to arrive runs the 256-thread select
// (two-level suffix scan + compact + bitonic — proven bit-exact in round 4).
__global__ __launch_bounds__(256) void k_class_sel(
    const float* __restrict__ logits, const float* __restrict__ boxreg,
    const float* __restrict__ pboxes, const float2* __restrict__ ms,
    u64* __restrict__ ckey, float4* __restrict__ cbox, int* __restrict__ corig,
    int* __restrict__ hist, int* __restrict__ counter, int* __restrict__ done,
    float* __restrict__ sel_score, int* __restrict__ sel_flat)
{
    int c = blockIdx.x;            // foreground class (label = c+1)
    int cl = c + 1;
    int t = threadIdx.x;

    // class-phase layout: skey64[N] | sbox[N] | sarea[N] | skeep[N] (32 KiB)
    // select-phase: keys[SELCAP] overlays the front 16 KiB (phases disjoint)
    __shared__ __align__(16) char smem[32768];
    u64*    skey64 = (u64*)smem;
    float4* sbox   = (float4*)(smem + 8192);
    float*  sarea  = (float*)(smem + 24576);
    int*    skeep  = (int*)(smem + 28672);
    __shared__ int scnt[256];
    __shared__ int sbstar, scount, sIsLast;
    __shared__ u64 wk[4];
    __shared__ int wp[4];

    // ============ class phase: score -> threshold -> sort -> NMS ===========
    float2 p0 = ms[t],       p1 = ms[t + 256];
    float2 p2 = ms[t + 512], p3 = ms[t + 768];
    float s0 = expf(logits[(t      ) * C + cl] - p0.x) / p0.y;
    float s1 = expf(logits[(t + 256) * C + cl] - p1.x) / p1.y;
    float s2 = expf(logits[(t + 512) * C + cl] - p2.x) / p2.y;
    float s3 = expf(logits[(t + 768) * C + cl] - p3.x) / p3.y;
    int f0 = s0 > SCORE_THRESH, f1 = s1 > SCORE_THRESH;
    int f2 = s2 > SCORE_THRESH, f3 = s3 > SCORE_THRESH;
    int mycount = f0 + f1 + f2 + f3;
    scnt[t] = mycount;
    __syncthreads();
    for (int off = 1; off < 256; off <<= 1) {
        int v = scnt[t];
        int a = (t >= off) ? scnt[t - off] : 0;
        __syncthreads();
        scnt[t] = v + a;
        __syncthreads();
    }
    int base = scnt[t] - mycount;
    int V = scnt[255];
    {
        int pos = base;
        if (f0) skey64[pos++] = ((u64)__float_as_uint(s0) << 32) | (u32)~(u32)(t);
        if (f1) skey64[pos++] = ((u64)__float_as_uint(s1) << 32) | (u32)~(u32)(t + 256);
        if (f2) skey64[pos++] = ((u64)__float_as_uint(s2) << 32) | (u32)~(u32)(t + 512);
        if (f3) skey64[pos++] = ((u64)__float_as_uint(s3) << 32) | (u32)~(u32)(t + 768);
    }
    __syncthreads();

    if (V > 0 && V <= 64) {
        if (t < 64) {
            int lane = t;
            u64 key = (lane < V) ? skey64[lane] : 0ull;
            // descending bitonic over 64 lanes (keys unique; 0-pad sinks)
            for (int k = 2; k <= 64; k <<= 1) {
                for (int j = k >> 1; j > 0; j >>= 1) {
                    u64 other = __shfl_xor(key, j);
                    bool takeMax = (((lane & j) == 0) == ((lane & k) == 0));
                    bool gt = key > other;
                    key = (takeMax == gt) ? key : other;
                }
            }
            bool act = key != 0ull;
            float4 b = make_float4(0.f, 0.f, 0.f, 0.f);
            float area = 0.0f;
            if (act) {
                int idx = (int)(~(u32)(key & 0xffffffffu));
                b = decode_box(pboxes, boxreg, idx, cl);
                area = (b.z - b.x + 1.0f) * (b.w - b.y + 1.0f);
                cbox[c * N + lane]  = b;
                corig[c * N + lane] = idx;
            }
            int kept = act ? 1 : 0;
            for (int i = 0; i + 1 < V; ++i) {
                int   ki  = __shfl(kept, i);
                float bix = __shfl(b.x, i), biy = __shfl(b.y, i);
                float biz = __shfl(b.z, i), biw = __shfl(b.w, i);
                float ai  = __shfl(area, i);
                if (ki && lane > i && kept) {
                    float lx = fmaxf(bix, b.x), ly = fmaxf(biy, b.y);
                    float rx = fminf(biz, b.z), ry = fminf(biw, b.w);
                    float ww = fmaxf(rx - lx + 1.0f, 0.0f);
                    float hh = fmaxf(ry - ly + 1.0f, 0.0f);
                    float inter = ww * hh;
                    float iou = inter / (ai + area - inter);
                    if (iou > NMS_THRESH) kept = 0;
                }
            }
            if (kept) {
                int pos = atomicAdd(counter, 1);
                u32 sb = (u32)(key >> 32);
                ckey[pos] = ((u64)sb << 32) | (u64)(u32)~(u32)(c * N + lane);
                atomicAdd(&hist[(int)(sb >> 16) - HBASE], 1);
            }
        }
    } else if (V > 64) {
        // ---------- fallback: LDS bitonic on P = next pow2 ----------
        int P = 128;
        while (P < V) P <<= 1;
        for (int i = V + t; i < P; i += 256) skey64[i] = 0ull;
        __syncthreads();
        for (int k = 2; k <= P; k <<= 1) {
            for (int j = k >> 1; j > 0; j >>= 1) {
                for (int i = t; i < P; i += 256) {
                    int ixj = i ^ j;
                    if (ixj > i) {
                        u64 a = skey64[i], bb = skey64[ixj];
                        bool desc = ((i & k) == 0);
                        if (desc ? (a < bb) : (a > bb)) { skey64[i] = bb; skey64[ixj] = a; }
                    }
                }
                __syncthreads();
            }
        }
        for (int p = t; p < V; p += 256) {
            int idx = (int)(~(u32)(skey64[p] & 0xffffffffu));
            float4 b = decode_box(pboxes, boxreg, idx, cl);
            sbox[p]  = b;
            sarea[p] = (b.z - b.x + 1.0f) * (b.w - b.y + 1.0f);
            skeep[p] = 1;
            cbox[c * N + p]  = b;
            corig[c * N + p] = idx;
        }
        __syncthreads();
        for (int i = 0; i < V; ++i) {
            if (skeep[i]) {
                float4 bi = sbox[i];
                float  ai = sarea[i];
                for (int j = i + 1 + t; j < V; j += 256) {
                    if (skeep[j]) {
                        float4 bj = sbox[j];
                        float lx = fmaxf(bi.x, bj.x), ly = fmaxf(bi.y, bj.y);
                        float rx = fminf(bi.z, bj.z), ry = fminf(bi.w, bj.w);
                        float ww = fmaxf(rx - lx + 1.0f, 0.0f);
                        float hh = fmaxf(ry - ly + 1.0f, 0.0f);
                        float inter = ww * hh;
                        float iou = inter / (ai + sarea[j] - inter);
                        if (iou > NMS_THRESH) skeep[j] = 0;
                    }
                }
            }
            __syncthreads();
        }
        for (int p = t; p < V; p += 256) {
            if (skeep[p]) {
                int pos = atomicAdd(counter, 1);
                u32 sb = (u32)(skey64[p] >> 32);
                ckey[pos] = ((u64)sb << 32) | (u64)(u32)~(u32)(c * N + p);
                atomicAdd(&hist[(int)(sb >> 16) - HBASE], 1);
            }
        }
    }

    // ============ arrive: release writes, last block proceeds ==============
    __threadfence();                 // release: ckey/hist/cbox/corig visible
    __syncthreads();
    if (t == 0) sIsLast = (atomicAdd(done, 1) == NC1 - 1);
    __syncthreads();
    if (!sIsLast) return;
    __threadfence();                 // acquire: see all other blocks' writes

    // ============ select phase (last block, 256 threads) ===================
    {
        int M = *counter;
        if (t == 0) { sbstar = 0; scount = 0; }

        // two-level suffix scan of 1024-bucket hist: thread t owns buckets
        // 4t..4t+3; same base arithmetic as the proven 1024-thread version.
        int h0 = hist[4 * t], h1 = hist[4 * t + 1];
        int h2 = hist[4 * t + 2], h3 = hist[4 * t + 3];
        int gs = h0 + h1 + h2 + h3;
        scnt[t] = gs;
        __syncthreads();
        for (int off = 1; off < 256; off <<= 1) {
            int v = scnt[t];
            int a = (t + off < 256) ? scnt[t + off] : 0;
            __syncthreads();
            scnt[t] = v + a;
            __syncthreads();
        }
        int above = scnt[t] - gs;            // keys in bucket-groups above t
        int b3 = above, b2 = b3 + h3, b1 = b2 + h2, b0 = b1 + h1;
        if (b0 < K && b0 + h0 >= K) sbstar = 4 * t;
        if (b1 < K && b1 + h1 >= K) sbstar = 4 * t + 1;
        if (b2 < K && b2 + h2 >= K) sbstar = 4 * t + 2;
        if (b3 < K && b3 + h3 >= K) sbstar = 4 * t + 3;
        __syncthreads();
        int bstar = sbstar;

        // compact keys with bucket >= bstar into LDS (overlays class smem)
        u64* keys = (u64*)smem;
        for (int p = t; p < M; p += 256) {
            u64 kk = ckey[p];
            int b = (int)((kk >> 48) & 0xFFFF) - HBASE;
            if (b >= bstar) {
                int pos = atomicAdd(&scount, 1);
                if (pos < SELCAP) keys[pos] = kk;
            }
        }
        __syncthreads();
        int cnt = scount;

        if (cnt > SELCAP) {
            // exact fallback (tie flood): K rounds of argmax over dense ckey
            for (int k = 0; k < K; ++k) {
                u64 key = 0ull; int pos = -1;
                for (int p = t; p < M; p += 256) {
                    u64 kk = ckey[p];
                    if (kk > key) { key = kk; pos = p; }
                }
                for (int off = 32; off; off >>= 1) {
                    u64 ok2 = __shfl_down(key, off);
                    int op  = __shfl_down(pos, off);
                    if (ok2 > key) { key = ok2; pos = op; }
                }
                if ((t & 63) == 0) { wk[t >> 6] = key; wp[t >> 6] = pos; }
                __syncthreads();
                if (t == 0) {
                    for (int w = 1; w < 4; ++w)
                        if (wk[w] > key) { key = wk[w]; pos = wp[w]; }
                    if (key != 0ull) {
                        sel_score[k] = __uint_as_float((u32)(key >> 32));
                        sel_flat[k]  = (int)(~(u32)(key & 0xffffffffu));
                        ckey[pos] = 0ull;
                    } else { sel_score[k] = 0.0f; sel_flat[k] = 0; }
                }
                __syncthreads();
            }
        } else {
            int P = 128;
            while (P < cnt) P <<= 1;
            for (int i = cnt + t; i < P; i += 256) keys[i] = 0ull;
            __syncthreads();
            for (int k = 2; k <= P; k <<= 1) {
                for (int j = k >> 1; j > 0; j >>= 1) {
                    for (int i = t; i < P; i += 256) {
                        int ixj = i ^ j;
                        if (ixj > i) {
                            u64 a = keys[i], b = keys[ixj];
                            bool desc = ((i & k) == 0);
                            if (desc ? (a < b) : (a > b)) { keys[i] = b; keys[ixj] = a; }
                        }
                    }
                    __syncthreads();
                }
            }
            if (t < K) {
                u64 key = keys[t];
                sel_score[t] = __uint_as_float((u32)(key >> 32));
                sel_flat[t]  = (int)(~(u32)(key & 0xffffffffu));
            }
        }
    }
}

// ---------------- gather outputs ------------------------------------------
// out layout: boxes[K*4] | scores[K] | feats[K*F] | labels[K]  (all f32)
__global__ __launch_bounds__(256) void k_gather(
    const float* __restrict__ sel_score, const int* __restrict__ sel_flat,
    const int* __restrict__ corig, const float4* __restrict__ cbox,
    const float* __restrict__ feats, float* __restrict__ out)
{
    int k = blockIdx.x, t = threadIdx.x;
    float s = sel_score[k];
    bool ok = s > 0.0f;
    float4 b = make_float4(0.f, 0.f, 0.f, 0.f);
    int label = 0, orig = 0;
    if (ok) {
        int flat = sel_flat[k];        // c*N + rank
        orig  = corig[flat];
        b     = cbox[flat];
        label = (flat >> 10) + 1;      // N = 1024
    }
    if (t == 0) {
        out[k * 4 + 0] = b.x; out[k * 4 + 1] = b.y;
        out[k * 4 + 2] = b.z; out[k * 4 + 3] = b.w;
        out[K * 4 + k] = ok ? s : 0.0f;
        out[K * 4 + K + K * F + k] = (float)label;
    }
    const float4* src = (const float4*)(feats + (size_t)orig * F);
    float4* dst = (float4*)(out + K * 4 + K + (size_t)k * F);
    float4 z = make_float4(0.f, 0.f, 0.f, 0.f);
    if (t < F / 4) dst[t] = ok ? src[t] : z;
}

// ---------------------------------------------------------------------------
extern "C" void kernel_launch(void* const* d_in, const int* in_sizes, int n_in,
                              void* d_out, int out_size, void* d_ws, size_t ws_size,
                              hipStream_t stream)
{
    const float* logits = (const float*)d_in[0];   // [N,C]
    const float* boxreg = (const float*)d_in[1];   // [N,C*4]
    const float* pboxes = (const float*)d_in[2];   // [N,4]
    const float* feats  = (const float*)d_in[3];   // [N,F]
    float* out = (float*)d_out;

    char* ws = (char*)d_ws;
    size_t off = 0;
    auto alloc = [&](size_t bytes) {
        size_t cur = off;
        off = (off + bytes + 255) & ~(size_t)255;
        return cur;
    };
    u64*    ckey      = (u64*)   (ws + alloc(sizeof(u64)    * MAXC));
    float4* cbox      = (float4*)(ws + alloc(sizeof(float4) * NC1 * N));
    int*    corig     = (int*)   (ws + alloc(sizeof(int)    * NC1 * N));
    float2* ms        = (float2*)(ws + alloc(sizeof(float2) * N));
    int*    hist      = (int*)   (ws + alloc(sizeof(int)    * HSIZE));
    int*    counter   = (int*)   (ws + alloc(sizeof(int)));
    int*    done      = (int*)   (ws + alloc(sizeof(int)));
    float*  sel_score = (float*) (ws + alloc(sizeof(float)  * K));
    int*    sel_flat  = (int*)   (ws + alloc(sizeof(int)    * K));

    hipLaunchKernelGGL(k_softmax, dim3(N / 4), dim3(256), 0, stream,
                       logits, ms, hist, counter, done);
    hipLaunchKernelGGL(k_class_sel, dim3(NC1), dim3(256), 0, stream,
                       logits, boxreg, pboxes, ms, ckey, cbox, corig,
                       hist, counter, done, sel_score, sel_flat);
    hipLaunchKernelGGL(k_gather, dim3(K), dim3(256), 0, stream,
                       sel_score, sel_flat, corig, cbox, feats, out);
}

// Round 6
// 99.158 us; speedup vs baseline: 2.3331x; 1.1257x over previous
//
#include <hip/hip_runtime.h>
#include <math.h>

#define N 1024
#define C 81
#define F 1024
#define K 100
#define NC1 80              // C-1 foreground classes
#define MAXC (NC1 * N)      // dense candidate capacity
#define HBASE 0x3D00        // hist bucket base: float bits >>16
#define HSIZE 1024          // covers score in (0.05, 1]: buckets 76..640
#define SELCAP 2048         // LDS select capacity

#define SCORE_THRESH 0.05f
#define NMS_THRESH   0.5f
#define BBOX_CLIP    4.135166556742356f   // log(1000/16)
#define IMG_W1       1215.0f
#define IMG_H1       799.0f

typedef unsigned long long u64;
typedef unsigned int u32;

// ---- decode one (proposal idx, class cl) box — expressions verbatim from the
// absmax==0 kernels so contraction/codegen matches.
__device__ float4 decode_box(const float* __restrict__ pboxes,
                             const float* __restrict__ boxreg, int idx, int cl)
{
    float4 pb = ((const float4*)pboxes)[idx];
    float4 r  = *(const float4*)(boxreg + (size_t)idx * (C * 4) + cl * 4);
    float w  = pb.z - pb.x + 1.0f, h = pb.w - pb.y + 1.0f;
    float cx = pb.x + 0.5f * w,  cy = pb.y + 0.5f * h;
    float dx = r.x / 10.0f, dy = r.y / 10.0f;
    float dw = fminf(r.z / 5.0f, BBOX_CLIP);
    float dh = fminf(r.w / 5.0f, BBOX_CLIP);
    float pcx = dx * w + cx, pcy = dy * h + cy;
    float pw = expf(dw) * w, ph = expf(dh) * h;
    float x1 = pcx - 0.5f * pw,        y1 = pcy - 0.5f * ph;
    float x2 = pcx + 0.5f * pw - 1.0f, y2 = pcy + 0.5f * ph - 1.0f;
    x1 = fminf(fmaxf(x1, 0.0f), IMG_W1);
    y1 = fminf(fmaxf(y1, 0.0f), IMG_H1);
    x2 = fminf(fmaxf(x2, 0.0f), IMG_W1);
    y2 = fminf(fmaxf(y2, 0.0f), IMG_H1);
    return make_float4(x1, y1, x2, y2);
}

// ---------------- per-row softmax stats (m, s), computed ONCE ---------------
// one wave per row, bit-exact replica of the original butterfly. Also zeroes
// hist + counter (grid covers HSIZE threads). ms[r] = (max, denom).
__global__ __launch_bounds__(256) void k_softmax(
    const float* __restrict__ logits, float2* __restrict__ ms,
    int* __restrict__ hist, int* __restrict__ counter)
{
    int gid = blockIdx.x * 256 + threadIdx.x;
    if (gid < HSIZE) hist[gid] = 0;
    if (gid == 0) *counter = 0;

    int n = blockIdx.x * 4 + (threadIdx.x >> 6);
    int t = threadIdx.x & 63;

    float v1 = logits[n * C + t];
    float v2 = (t < C - 64) ? logits[n * C + 64 + t] : -INFINITY;
    float m = fmaxf(v1, v2);
    for (int off = 32; off; off >>= 1) m = fmaxf(m, __shfl_xor(m, off));
    float e1 = expf(v1 - m);
    float e2 = (t < C - 64) ? expf(v2 - m) : 0.0f;
    float s = e1 + e2;
    for (int off = 32; off; off >>= 1) s += __shfl_xor(s, off);

    if (t == 0) ms[n] = make_float2(m, s);
}

// ---------------- per-class: score -> threshold -> sort -> NMS --------------
// one block per foreground class. Compaction via per-wave ballot (order-free:
// keys are unique and fully sorted before any use, so any placement order
// yields identical results). NMS paths:
//   V <= 64      : wave shuffle bitonic + shuffle-broadcast walk (proven)
//   64 < V <=256 : LDS bitonic + parallel suppression-bitmask matrix +
//                  barrier-free single-wave walk (bit-identical semantics)
//   V > 256      : old barrier-per-row fallback (safety; not hit in practice)
__global__ __launch_bounds__(256) void k_class(
    const float* __restrict__ logits, const float* __restrict__ boxreg,
    const float* __restrict__ pboxes, const float2* __restrict__ ms,
    u64* __restrict__ ckey, float4* __restrict__ cbox, int* __restrict__ corig,
    int* __restrict__ hist, int* __restrict__ counter)
{
    int c = blockIdx.x;            // foreground class (label = c+1)
    int cl = c + 1;
    int t = threadIdx.x;
    int lane = t & 63, wv = t >> 6;

    __shared__ u64    skey64[N];
    __shared__ float4 sbox[N];
    __shared__ float  sarea[N];
    __shared__ int    skeep[N];
    __shared__ u64    sup[256][4];     // suppression matrix for V<=256
    __shared__ u64    skw[4];          // final keep words
    __shared__ int    swc[4];          // per-wave candidate counts

    // ---- scores (identical bits to old probsT entries) ----
    float2 p0 = ms[t],       p1 = ms[t + 256];
    float2 p2 = ms[t + 512], p3 = ms[t + 768];
    float s0 = expf(logits[(t      ) * C + cl] - p0.x) / p0.y;
    float s1 = expf(logits[(t + 256) * C + cl] - p1.x) / p1.y;
    float s2 = expf(logits[(t + 512) * C + cl] - p2.x) / p2.y;
    float s3 = expf(logits[(t + 768) * C + cl] - p3.x) / p3.y;
    int f0 = s0 > SCORE_THRESH, f1 = s1 > SCORE_THRESH;
    int f2 = s2 > SCORE_THRESH, f3 = s3 > SCORE_THRESH;

    // ---- ballot compaction (2 barriers instead of 16) ----
    u64 lmask = (1ull << lane) - 1ull;
    u64 b0 = __ballot(f0), b1 = __ballot(f1);
    u64 b2 = __ballot(f2), b3 = __ballot(f3);
    int wcount = __popcll(b0) + __popcll(b1) + __popcll(b2) + __popcll(b3);
    if (lane == 0) swc[wv] = wcount;
    __syncthreads();
    int w0c = swc[0], w1c = swc[1], w2c = swc[2], w3c = swc[3];
    int V = w0c + w1c + w2c + w3c;
    int wbase = (wv > 0 ? w0c : 0) + (wv > 1 ? w1c : 0) + (wv > 2 ? w2c : 0);
    {
        int o0 = wbase;
        int o1 = o0 + __popcll(b0);
        int o2 = o1 + __popcll(b1);
        int o3 = o2 + __popcll(b2);
        if (f0) skey64[o0 + __popcll(b0 & lmask)] =
            ((u64)__float_as_uint(s0) << 32) | (u32)~(u32)(t);
        if (f1) skey64[o1 + __popcll(b1 & lmask)] =
            ((u64)__float_as_uint(s1) << 32) | (u32)~(u32)(t + 256);
        if (f2) skey64[o2 + __popcll(b2 & lmask)] =
            ((u64)__float_as_uint(s2) << 32) | (u32)~(u32)(t + 512);
        if (f3) skey64[o3 + __popcll(b3 & lmask)] =
            ((u64)__float_as_uint(s3) << 32) | (u32)~(u32)(t + 768);
    }
    __syncthreads();
    if (V == 0) return;

    if (V <= 64) {
        // ---------- proven wave path ----------
        if (t < 64) {
            u64 key = (lane < V) ? skey64[lane] : 0ull;
            // descending bitonic over 64 lanes (keys unique; 0-pad sinks)
            for (int k = 2; k <= 64; k <<= 1) {
                for (int j = k >> 1; j > 0; j >>= 1) {
                    u64 other = __shfl_xor(key, j);
                    bool takeMax = (((lane & j) == 0) == ((lane & k) == 0));
                    bool gt = key > other;
                    key = (takeMax == gt) ? key : other;
                }
            }
            bool act = key != 0ull;
            float4 b = make_float4(0.f, 0.f, 0.f, 0.f);
            float area = 0.0f;
            if (act) {
                int idx = (int)(~(u32)(key & 0xffffffffu));
                b = decode_box(pboxes, boxreg, idx, cl);
                area = (b.z - b.x + 1.0f) * (b.w - b.y + 1.0f);
                cbox[c * N + lane]  = b;
                corig[c * N + lane] = idx;
            }
            int kept = act ? 1 : 0;
            for (int i = 0; i + 1 < V; ++i) {
                int   ki  = __shfl(kept, i);
                float bix = __shfl(b.x, i), biy = __shfl(b.y, i);
                float biz = __shfl(b.z, i), biw = __shfl(b.w, i);
                float ai  = __shfl(area, i);
                if (ki && lane > i && kept) {
                    float lx = fmaxf(bix, b.x), ly = fmaxf(biy, b.y);
                    float rx = fminf(biz, b.z), ry = fminf(biw, b.w);
                    float ww = fmaxf(rx - lx + 1.0f, 0.0f);
                    float hh = fmaxf(ry - ly + 1.0f, 0.0f);
                    float inter = ww * hh;
                    float iou = inter / (ai + area - inter);
                    if (iou > NMS_THRESH) kept = 0;
                }
            }
            if (kept) {
                int pos = atomicAdd(counter, 1);
                u32 sb = (u32)(key >> 32);
                ckey[pos] = ((u64)sb << 32) | (u64)(u32)~(u32)(c * N + lane);
                atomicAdd(&hist[(int)(sb >> 16) - HBASE], 1);
            }
        }
        return;
    }

    if (V <= 256) {
        // ---------- LDS bitonic sort on P = next pow2 (<=256) ----------
        int P = 128;
        while (P < V) P <<= 1;
        for (int i = V + t; i < P; i += 256) skey64[i] = 0ull;
        __syncthreads();
        for (int k = 2; k <= P; k <<= 1) {
            for (int j = k >> 1; j > 0; j >>= 1) {
                if (t < P) {
                    int i = t, ixj = i ^ j;
                    if (ixj > i) {
                        u64 a = skey64[i], bb = skey64[ixj];
                        bool desc = ((i & k) == 0);
                        if (desc ? (a < bb) : (a > bb)) { skey64[i] = bb; skey64[ixj] = a; }
                    }
                }
                __syncthreads();
            }
        }
        // decode sorted candidates
        for (int p = t; p < V; p += 256) {
            int idx = (int)(~(u32)(skey64[p] & 0xffffffffu));
            float4 b = decode_box(pboxes, boxreg, idx, cl);
            sbox[p]  = b;
            sarea[p] = (b.z - b.x + 1.0f) * (b.w - b.y + 1.0f);
            cbox[c * N + p]  = b;
            corig[c * N + p] = idx;
        }
        __syncthreads();
        // parallel suppression matrix: row i, bit j (j>i): iou(i,j) > T
        for (int i = t; i < V; i += 256) {
            float4 bi = sbox[i];
            float  ai = sarea[i];
            u64 w[4] = {0ull, 0ull, 0ull, 0ull};
            #pragma unroll
            for (int g = 0; g < 4; ++g) {
                int jlo = (i + 1 > g * 64) ? i + 1 : g * 64;
                int jhi = (V < (g + 1) * 64) ? V : (g + 1) * 64;
                for (int j = jlo; j < jhi; ++j) {
                    float4 bj = sbox[j];
                    float lx = fmaxf(bi.x, bj.x), ly = fmaxf(bi.y, bj.y);
                    float rx = fminf(bi.z, bj.z), ry = fminf(bi.w, bj.w);
                    float ww = fmaxf(rx - lx + 1.0f, 0.0f);
                    float hh = fmaxf(ry - ly + 1.0f, 0.0f);
                    float inter = ww * hh;
                    float iou = inter / (ai + sarea[j] - inter);
                    if (iou > NMS_THRESH) w[g] |= 1ull << (j & 63);
                }
            }
            sup[i][0] = w[0]; sup[i][1] = w[1];
            sup[i][2] = w[2]; sup[i][3] = w[3];
        }
        __syncthreads();
        // barrier-free walk on wave 0: rows register-resident, rows via shfl.
        // Semantics identical to: for i asc: if keep[i]: keep &= ~sup[i].
        if (t < 64) {
            u64 r0w0 = sup[t][0], r0w1 = sup[t][1], r0w2 = sup[t][2], r0w3 = sup[t][3];
            u64 r1w1 = 0, r1w2 = 0, r1w3 = 0;
            u64 r2w2 = 0, r2w3 = 0;
            u64 r3w3 = 0;
            if (64 + t < V)  { r1w1 = sup[64 + t][1];  r1w2 = sup[64 + t][2];  r1w3 = sup[64 + t][3]; }
            if (128 + t < V) { r2w2 = sup[128 + t][2]; r2w3 = sup[128 + t][3]; }
            if (192 + t < V) { r3w3 = sup[192 + t][3]; }
            // (row in group g has no bits below word g: suppressee j > row idx)
            u64 k0 = ~0ull, k1 = ~0ull, k2 = ~0ull, k3 = ~0ull;
            {
                int lim = (V < 64) ? V : 64;
                for (int i = 0; i < lim; ++i)
                    if ((k0 >> i) & 1) {
                        k0 &= ~__shfl(r0w0, i); k1 &= ~__shfl(r0w1, i);
                        k2 &= ~__shfl(r0w2, i); k3 &= ~__shfl(r0w3, i);
                    }
            }
            if (V > 64) {
                int lim = (V - 64 < 64) ? V - 64 : 64;
                for (int i = 0; i < lim; ++i)
                    if ((k1 >> i) & 1) {
                        k1 &= ~__shfl(r1w1, i);
                        k2 &= ~__shfl(r1w2, i); k3 &= ~__shfl(r1w3, i);
                    }
            }
            if (V > 128) {
                int lim = (V - 128 < 64) ? V - 128 : 64;
                for (int i = 0; i < lim; ++i)
                    if ((k2 >> i) & 1) {
                        k2 &= ~__shfl(r2w2, i); k3 &= ~__shfl(r2w3, i);
                    }
            }
            if (V > 192) {
                int lim = V - 192;
                for (int i = 0; i < lim; ++i)
                    if ((k3 >> i) & 1) k3 &= ~__shfl(r3w3, i);
            }
            if (t == 0) { skw[0] = k0; skw[1] = k1; skw[2] = k2; skw[3] = k3; }
        }
        __syncthreads();
        for (int p = t; p < V; p += 256) {
            if ((skw[p >> 6] >> (p & 63)) & 1ull) {
                int pos = atomicAdd(counter, 1);
                u32 sb = (u32)(skey64[p] >> 32);
                ckey[pos] = ((u64)sb << 32) | (u64)(u32)~(u32)(c * N + p);
                atomicAdd(&hist[(int)(sb >> 16) - HBASE], 1);
            }
        }
        return;
    }

    // ---------- safety fallback: V > 256 (not hit at these stats) ----------
    {
        int P = 512;
        while (P < V) P <<= 1;
        for (int i = V + t; i < P; i += 256) skey64[i] = 0ull;
        __syncthreads();
        for (int k = 2; k <= P; k <<= 1) {
            for (int j = k >> 1; j > 0; j >>= 1) {
                for (int i = t; i < P; i += 256) {
                    int ixj = i ^ j;
                    if (ixj > i) {
                        u64 a = skey64[i], bb = skey64[ixj];
                        bool desc = ((i & k) == 0);
                        if (desc ? (a < bb) : (a > bb)) { skey64[i] = bb; skey64[ixj] = a; }
                    }
                }
                __syncthreads();
            }
        }
        for (int p = t; p < V; p += 256) {
            int idx = (int)(~(u32)(skey64[p] & 0xffffffffu));
            float4 b = decode_box(pboxes, boxreg, idx, cl);
            sbox[p]  = b;
            sarea[p] = (b.z - b.x + 1.0f) * (b.w - b.y + 1.0f);
            skeep[p] = 1;
            cbox[c * N + p]  = b;
            corig[c * N + p] = idx;
        }
        __syncthreads();
        for (int i = 0; i < V; ++i) {
            if (skeep[i]) {
                float4 bi = sbox[i];
                float  ai = sarea[i];
                for (int j = i + 1 + t; j < V; j += 256) {
                    if (skeep[j]) {
                        float4 bj = sbox[j];
                        float lx = fmaxf(bi.x, bj.x), ly = fmaxf(bi.y, bj.y);
                        float rx = fminf(bi.z, bj.z), ry = fminf(bi.w, bj.w);
                        float ww = fmaxf(rx - lx + 1.0f, 0.0f);
                        float hh = fmaxf(ry - ly + 1.0f, 0.0f);
                        float inter = ww * hh;
                        float iou = inter / (ai + sarea[j] - inter);
                        if (iou > NMS_THRESH) skeep[j] = 0;
                    }
                }
            }
            __syncthreads();
        }
        for (int p = t; p < V; p += 256) {
            if (skeep[p]) {
                int pos = atomicAdd(counter, 1);
                u32 sb = (u32)(skey64[p] >> 32);
                ckey[pos] = ((u64)sb << 32) | (u64)(u32)~(u32)(c * N + p);
                atomicAdd(&hist[(int)(sb >> 16) - HBASE], 1);
            }
        }
    }
}

// ---------------- exact top-K via radix-select + small bitonic sort --------
__global__ __launch_bounds__(1024) void k_select(
    const int* __restrict__ counter, u64* ckey, const int* __restrict__ hist,
    float* __restrict__ sel_score, int* __restrict__ sel_flat)
{
    int t = threadIdx.x;
    __shared__ u64 keys[SELCAP];
    __shared__ int partial[1024];
    __shared__ int sb_bstar, scount;
    __shared__ u64 wk[16];
    __shared__ int wp[16];

    int M = *counter;
    if (t == 0) { sb_bstar = 0; scount = 0; }

    // phase 1: suffix scan of 1024-bucket histogram -> bucket of K-th key
    int lsum = hist[t];
    partial[t] = lsum;
    __syncthreads();
    for (int off = 1; off < 1024; off <<= 1) {
        int v = partial[t];
        int a = (t + off < 1024) ? partial[t + off] : 0;
        __syncthreads();
        partial[t] = v + a;
        __syncthreads();
    }
    int base = partial[t] - lsum;              // keys in buckets above t
    if (base < K && base + lsum >= K) sb_bstar = t;
    __syncthreads();
    int bstar = sb_bstar;

    // phase 2: compact keys with bucket >= bstar
    for (int p = t; p < M; p += 1024) {
        u64 kk = ckey[p];
        int b = (int)((kk >> 48) & 0xFFFF) - HBASE;
        if (b >= bstar) {
            int pos = atomicAdd(&scount, 1);
            if (pos < SELCAP) keys[pos] = kk;
        }
    }
    __syncthreads();
    int cnt = scount;

    if (cnt > SELCAP) {
        // exact fallback (tie flood): K rounds of argmax over dense ckey
        for (int k = 0; k < K; ++k) {
            u64 key = 0ull; int pos = -1;
            for (int p = t; p < M; p += 1024) {
                u64 kk = ckey[p];
                if (kk > key) { key = kk; pos = p; }
            }
            for (int off = 32; off; off >>= 1) {
                u64 ok2 = __shfl_down(key, off);
                int op = __shfl_down(pos, off);
                if (ok2 > key) { key = ok2; pos = op; }
            }
            if ((t & 63) == 0) { wk[t >> 6] = key; wp[t >> 6] = pos; }
            __syncthreads();
            if (t == 0) {
                for (int w = 1; w < 16; ++w)
                    if (wk[w] > key) { key = wk[w]; pos = wp[w]; }
                if (key != 0ull) {
                    sel_score[k] = __uint_as_float((u32)(key >> 32));
                    sel_flat[k]  = (int)(~(u32)(key & 0xffffffffu));
                    ckey[pos] = 0ull;
                } else { sel_score[k] = 0.0f; sel_flat[k] = 0; }
            }
            __syncthreads();
        }
        return;
    }

    // phase 3: bitonic sort padded selection, emit top K
    int P = 128;
    while (P < cnt) P <<= 1;
    for (int i = cnt + t; i < P; i += 1024) keys[i] = 0ull;
    __syncthreads();
    for (int k = 2; k <= P; k <<= 1) {
        for (int j = k >> 1; j > 0; j >>= 1) {
            for (int i = t; i < P; i += 1024) {
                int ixj = i ^ j;
                if (ixj > i) {
                    u64 a = keys[i], b = keys[ixj];
                    bool desc = ((i & k) == 0);
                    if (desc ? (a < b) : (a > b)) { keys[i] = b; keys[ixj] = a; }
                }
            }
            __syncthreads();
        }
    }
    if (t < K) {
        u64 key = keys[t];
        sel_score[t] = __uint_as_float((u32)(key >> 32));
        sel_flat[t]  = (int)(~(u32)(key & 0xffffffffu));
    }
}

// ---------------- gather outputs ------------------------------------------
// out layout: boxes[K*4] | scores[K] | feats[K*F] | labels[K]  (all f32)
__global__ __launch_bounds__(256) void k_gather(
    const float* __restrict__ sel_score, const int* __restrict__ sel_flat,
    const int* __restrict__ corig, const float4* __restrict__ cbox,
    const float* __restrict__ feats, float* __restrict__ out)
{
    int k = blockIdx.x, t = threadIdx.x;
    float s = sel_score[k];
    bool ok = s > 0.0f;
    float4 b = make_float4(0.f, 0.f, 0.f, 0.f);
    int label = 0, orig = 0;
    if (ok) {
        int flat = sel_flat[k];        // c*N + rank
        orig  = corig[flat];
        b     = cbox[flat];
        label = (flat >> 10) + 1;      // N = 1024
    }
    if (t == 0) {
        out[k * 4 + 0] = b.x; out[k * 4 + 1] = b.y;
        out[k * 4 + 2] = b.z; out[k * 4 + 3] = b.w;
        out[K * 4 + k] = ok ? s : 0.0f;
        out[K * 4 + K + K * F + k] = (float)label;
    }
    const float4* src = (const float4*)(feats + (size_t)orig * F);
    float4* dst = (float4*)(out + K * 4 + K + (size_t)k * F);
    float4 z = make_float4(0.f, 0.f, 0.f, 0.f);
    if (t < F / 4) dst[t] = ok ? src[t] : z;
}

// ---------------------------------------------------------------------------
extern "C" void kernel_launch(void* const* d_in, const int* in_sizes, int n_in,
                              void* d_out, int out_size, void* d_ws, size_t ws_size,
                              hipStream_t stream)
{
    const float* logits = (const float*)d_in[0];   // [N,C]
    const float* boxreg = (const float*)d_in[1];   // [N,C*4]
    const float* pboxes = (const float*)d_in[2];   // [N,4]
    const float* feats  = (const float*)d_in[3];   // [N,F]
    float* out = (float*)d_out;

    char* ws = (char*)d_ws;
    size_t off = 0;
    auto alloc = [&](size_t bytes) {
        size_t cur = off;
        off = (off + bytes + 255) & ~(size_t)255;
        return cur;
    };
    u64*    ckey      = (u64*)   (ws + alloc(sizeof(u64)    * MAXC));
    float4* cbox      = (float4*)(ws + alloc(sizeof(float4) * NC1 * N));
    int*    corig     = (int*)   (ws + alloc(sizeof(int)    * NC1 * N));
    float2* ms        = (float2*)(ws + alloc(sizeof(float2) * N));
    int*    hist      = (int*)   (ws + alloc(sizeof(int)    * HSIZE));
    int*    counter   = (int*)   (ws + alloc(sizeof(int)));
    float*  sel_score = (float*) (ws + alloc(sizeof(float)  * K));
    int*    sel_flat  = (int*)   (ws + alloc(sizeof(int)    * K));

    hipLaunchKernelGGL(k_softmax, dim3(N / 4), dim3(256), 0, stream,
                       logits, ms, hist, counter);
    hipLaunchKernelGGL(k_class, dim3(NC1), dim3(256), 0, stream,
                       logits, boxreg, pboxes, ms, ckey, cbox, corig, hist, counter);
    hipLaunchKernelGGL(k_select, dim3(1), dim3(1024), 0, stream,
                       counter, ckey, hist, sel_score, sel_flat);
    hipLaunchKernelGGL(k_gather, dim3(K), dim3(256), 0, stream,
                       sel_score, sel_flat, corig, cbox, feats, out);
}

// Round 7
// 96.802 us; speedup vs baseline: 2.3898x; 1.0243x over previous
//
#include <hip/hip_runtime.h>
#include <math.h>

#define N 1024
#define C 81
#define F 1024
#define K 100
#define NC1 80              // C-1 foreground classes
#define MAXC (NC1 * N)      // dense candidate capacity
#define HBASE 0x3D00        // hist bucket base: float bits >>16
#define HSIZE 1024          // covers score in (0.05, 1]: buckets 76..640
#define SELCAP 2048         // LDS select capacity

#define SCORE_THRESH 0.05f
#define NMS_THRESH   0.5f
#define BBOX_CLIP    4.135166556742356f   // log(1000/16)
#define IMG_W1       1215.0f
#define IMG_H1       799.0f

typedef unsigned long long u64;
typedef unsigned int u32;

// ---- decode one (proposal idx, class cl) box — expressions verbatim from the
// absmax==0 kernels so contraction/codegen matches.
__device__ float4 decode_box(const float* __restrict__ pboxes,
                             const float* __restrict__ boxreg, int idx, int cl)
{
    float4 pb = ((const float4*)pboxes)[idx];
    float4 r  = *(const float4*)(boxreg + (size_t)idx * (C * 4) + cl * 4);
    float w  = pb.z - pb.x + 1.0f, h = pb.w - pb.y + 1.0f;
    float cx = pb.x + 0.5f * w,  cy = pb.y + 0.5f * h;
    float dx = r.x / 10.0f, dy = r.y / 10.0f;
    float dw = fminf(r.z / 5.0f, BBOX_CLIP);
    float dh = fminf(r.w / 5.0f, BBOX_CLIP);
    float pcx = dx * w + cx, pcy = dy * h + cy;
    float pw = expf(dw) * w, ph = expf(dh) * h;
    float x1 = pcx - 0.5f * pw,        y1 = pcy - 0.5f * ph;
    float x2 = pcx + 0.5f * pw - 1.0f, y2 = pcy + 0.5f * ph - 1.0f;
    x1 = fminf(fmaxf(x1, 0.0f), IMG_W1);
    y1 = fminf(fmaxf(y1, 0.0f), IMG_H1);
    x2 = fminf(fmaxf(x2, 0.0f), IMG_W1);
    y2 = fminf(fmaxf(y2, 0.0f), IMG_H1);
    return make_float4(x1, y1, x2, y2);
}

// ---------------- per-row softmax stats (m, s), computed ONCE ---------------
// one wave per row, bit-exact replica of the original butterfly. Also zeroes
// hist + counter (grid covers HSIZE threads). ms[r] = (max, denom).
__global__ __launch_bounds__(256) void k_softmax(
    const float* __restrict__ logits, float2* __restrict__ ms,
    int* __restrict__ hist, int* __restrict__ counter)
{
    int gid = blockIdx.x * 256 + threadIdx.x;
    if (gid < HSIZE) hist[gid] = 0;
    if (gid == 0) *counter = 0;

    int n = blockIdx.x * 4 + (threadIdx.x >> 6);
    int t = threadIdx.x & 63;

    float v1 = logits[n * C + t];
    float v2 = (t < C - 64) ? logits[n * C + 64 + t] : -INFINITY;
    float m = fmaxf(v1, v2);
    for (int off = 32; off; off >>= 1) m = fmaxf(m, __shfl_xor(m, off));
    float e1 = expf(v1 - m);
    float e2 = (t < C - 64) ? expf(v2 - m) : 0.0f;
    float s = e1 + e2;
    for (int off = 32; off; off >>= 1) s += __shfl_xor(s, off);

    if (t == 0) ms[n] = make_float2(m, s);
}

// ---------------- per-class: score -> threshold -> sort -> NMS --------------
// one block per foreground class. Compaction via per-wave ballot (order-free:
// keys are unique and fully sorted before any use, so any placement order
// yields identical results). NMS paths:
//   V <= 64      : wave shuffle bitonic + shuffle-broadcast walk (proven)
//   64 < V <=256 : LDS bitonic + parallel suppression-bitmask matrix +
//                  barrier-free single-wave walk (proven round 6)
//   V > 256      : old barrier-per-row fallback (safety; not hit in practice)
__global__ __launch_bounds__(256) void k_class(
    const float* __restrict__ logits, const float* __restrict__ boxreg,
    const float* __restrict__ pboxes, const float2* __restrict__ ms,
    u64* __restrict__ ckey, float4* __restrict__ cbox, int* __restrict__ corig,
    int* __restrict__ hist, int* __restrict__ counter)
{
    int c = blockIdx.x;            // foreground class (label = c+1)
    int cl = c + 1;
    int t = threadIdx.x;
    int lane = t & 63, wv = t >> 6;

    __shared__ u64    skey64[N];
    __shared__ float4 sbox[N];
    __shared__ float  sarea[N];
    __shared__ int    skeep[N];
    __shared__ u64    sup[256][4];     // suppression matrix for V<=256
    __shared__ u64    skw[4];          // final keep words
    __shared__ int    swc[4];          // per-wave candidate counts

    // ---- scores (identical bits to old probsT entries) ----
    float2 p0 = ms[t],       p1 = ms[t + 256];
    float2 p2 = ms[t + 512], p3 = ms[t + 768];
    float s0 = expf(logits[(t      ) * C + cl] - p0.x) / p0.y;
    float s1 = expf(logits[(t + 256) * C + cl] - p1.x) / p1.y;
    float s2 = expf(logits[(t + 512) * C + cl] - p2.x) / p2.y;
    float s3 = expf(logits[(t + 768) * C + cl] - p3.x) / p3.y;
    int f0 = s0 > SCORE_THRESH, f1 = s1 > SCORE_THRESH;
    int f2 = s2 > SCORE_THRESH, f3 = s3 > SCORE_THRESH;

    // ---- ballot compaction (2 barriers instead of 16) ----
    u64 lmask = (1ull << lane) - 1ull;
    u64 b0 = __ballot(f0), b1 = __ballot(f1);
    u64 b2 = __ballot(f2), b3 = __ballot(f3);
    int wcount = __popcll(b0) + __popcll(b1) + __popcll(b2) + __popcll(b3);
    if (lane == 0) swc[wv] = wcount;
    __syncthreads();
    int w0c = swc[0], w1c = swc[1], w2c = swc[2], w3c = swc[3];
    int V = w0c + w1c + w2c + w3c;
    int wbase = (wv > 0 ? w0c : 0) + (wv > 1 ? w1c : 0) + (wv > 2 ? w2c : 0);
    {
        int o0 = wbase;
        int o1 = o0 + __popcll(b0);
        int o2 = o1 + __popcll(b1);
        int o3 = o2 + __popcll(b2);
        if (f0) skey64[o0 + __popcll(b0 & lmask)] =
            ((u64)__float_as_uint(s0) << 32) | (u32)~(u32)(t);
        if (f1) skey64[o1 + __popcll(b1 & lmask)] =
            ((u64)__float_as_uint(s1) << 32) | (u32)~(u32)(t + 256);
        if (f2) skey64[o2 + __popcll(b2 & lmask)] =
            ((u64)__float_as_uint(s2) << 32) | (u32)~(u32)(t + 512);
        if (f3) skey64[o3 + __popcll(b3 & lmask)] =
            ((u64)__float_as_uint(s3) << 32) | (u32)~(u32)(t + 768);
    }
    __syncthreads();
    if (V == 0) return;

    if (V <= 64) {
        // ---------- proven wave path ----------
        if (t < 64) {
            u64 key = (lane < V) ? skey64[lane] : 0ull;
            // descending bitonic over 64 lanes (keys unique; 0-pad sinks)
            for (int k = 2; k <= 64; k <<= 1) {
                for (int j = k >> 1; j > 0; j >>= 1) {
                    u64 other = __shfl_xor(key, j);
                    bool takeMax = (((lane & j) == 0) == ((lane & k) == 0));
                    bool gt = key > other;
                    key = (takeMax == gt) ? key : other;
                }
            }
            bool act = key != 0ull;
            float4 b = make_float4(0.f, 0.f, 0.f, 0.f);
            float area = 0.0f;
            if (act) {
                int idx = (int)(~(u32)(key & 0xffffffffu));
                b = decode_box(pboxes, boxreg, idx, cl);
                area = (b.z - b.x + 1.0f) * (b.w - b.y + 1.0f);
                cbox[c * N + lane]  = b;
                corig[c * N + lane] = idx;
            }
            int kept = act ? 1 : 0;
            for (int i = 0; i + 1 < V; ++i) {
                int   ki  = __shfl(kept, i);
                float bix = __shfl(b.x, i), biy = __shfl(b.y, i);
                float biz = __shfl(b.z, i), biw = __shfl(b.w, i);
                float ai  = __shfl(area, i);
                if (ki && lane > i && kept) {
                    float lx = fmaxf(bix, b.x), ly = fmaxf(biy, b.y);
                    float rx = fminf(biz, b.z), ry = fminf(biw, b.w);
                    float ww = fmaxf(rx - lx + 1.0f, 0.0f);
                    float hh = fmaxf(ry - ly + 1.0f, 0.0f);
                    float inter = ww * hh;
                    float iou = inter / (ai + area - inter);
                    if (iou > NMS_THRESH) kept = 0;
                }
            }
            if (kept) {
                int pos = atomicAdd(counter, 1);
                u32 sb = (u32)(key >> 32);
                ckey[pos] = ((u64)sb << 32) | (u64)(u32)~(u32)(c * N + lane);
                atomicAdd(&hist[(int)(sb >> 16) - HBASE], 1);
            }
        }
        return;
    }

    if (V <= 256) {
        // ---------- LDS bitonic sort on P = next pow2 (<=256) ----------
        int P = 128;
        while (P < V) P <<= 1;
        for (int i = V + t; i < P; i += 256) skey64[i] = 0ull;
        __syncthreads();
        for (int k = 2; k <= P; k <<= 1) {
            for (int j = k >> 1; j > 0; j >>= 1) {
                if (t < P) {
                    int i = t, ixj = i ^ j;
                    if (ixj > i) {
                        u64 a = skey64[i], bb = skey64[ixj];
                        bool desc = ((i & k) == 0);
                        if (desc ? (a < bb) : (a > bb)) { skey64[i] = bb; skey64[ixj] = a; }
                    }
                }
                __syncthreads();
            }
        }
        // decode sorted candidates
        for (int p = t; p < V; p += 256) {
            int idx = (int)(~(u32)(skey64[p] & 0xffffffffu));
            float4 b = decode_box(pboxes, boxreg, idx, cl);
            sbox[p]  = b;
            sarea[p] = (b.z - b.x + 1.0f) * (b.w - b.y + 1.0f);
            cbox[c * N + p]  = b;
            corig[c * N + p] = idx;
        }
        __syncthreads();
        // parallel suppression matrix: row i, bit j (j>i): iou(i,j) > T
        for (int i = t; i < V; i += 256) {
            float4 bi = sbox[i];
            float  ai = sarea[i];
            u64 w[4] = {0ull, 0ull, 0ull, 0ull};
            #pragma unroll
            for (int g = 0; g < 4; ++g) {
                int jlo = (i + 1 > g * 64) ? i + 1 : g * 64;
                int jhi = (V < (g + 1) * 64) ? V : (g + 1) * 64;
                for (int j = jlo; j < jhi; ++j) {
                    float4 bj = sbox[j];
                    float lx = fmaxf(bi.x, bj.x), ly = fmaxf(bi.y, bj.y);
                    float rx = fminf(bi.z, bj.z), ry = fminf(bi.w, bj.w);
                    float ww = fmaxf(rx - lx + 1.0f, 0.0f);
                    float hh = fmaxf(ry - ly + 1.0f, 0.0f);
                    float inter = ww * hh;
                    float iou = inter / (ai + sarea[j] - inter);
                    if (iou > NMS_THRESH) w[g] |= 1ull << (j & 63);
                }
            }
            sup[i][0] = w[0]; sup[i][1] = w[1];
            sup[i][2] = w[2]; sup[i][3] = w[3];
        }
        __syncthreads();
        // barrier-free walk on wave 0: rows register-resident, rows via shfl.
        // Semantics identical to: for i asc: if keep[i]: keep &= ~sup[i].
        if (t < 64) {
            u64 r0w0 = sup[t][0], r0w1 = sup[t][1], r0w2 = sup[t][2], r0w3 = sup[t][3];
            u64 r1w1 = 0, r1w2 = 0, r1w3 = 0;
            u64 r2w2 = 0, r2w3 = 0;
            u64 r3w3 = 0;
            if (64 + t < V)  { r1w1 = sup[64 + t][1];  r1w2 = sup[64 + t][2];  r1w3 = sup[64 + t][3]; }
            if (128 + t < V) { r2w2 = sup[128 + t][2]; r2w3 = sup[128 + t][3]; }
            if (192 + t < V) { r3w3 = sup[192 + t][3]; }
            // (row in group g has no bits below word g: suppressee j > row idx)
            u64 k0 = ~0ull, k1 = ~0ull, k2 = ~0ull, k3 = ~0ull;
            {
                int lim = (V < 64) ? V : 64;
                for (int i = 0; i < lim; ++i)
                    if ((k0 >> i) & 1) {
                        k0 &= ~__shfl(r0w0, i); k1 &= ~__shfl(r0w1, i);
                        k2 &= ~__shfl(r0w2, i); k3 &= ~__shfl(r0w3, i);
                    }
            }
            if (V > 64) {
                int lim = (V - 64 < 64) ? V - 64 : 64;
                for (int i = 0; i < lim; ++i)
                    if ((k1 >> i) & 1) {
                        k1 &= ~__shfl(r1w1, i);
                        k2 &= ~__shfl(r1w2, i); k3 &= ~__shfl(r1w3, i);
                    }
            }
            if (V > 128) {
                int lim = (V - 128 < 64) ? V - 128 : 64;
                for (int i = 0; i < lim; ++i)
                    if ((k2 >> i) & 1) {
                        k2 &= ~__shfl(r2w2, i); k3 &= ~__shfl(r2w3, i);
                    }
            }
            if (V > 192) {
                int lim = V - 192;
                for (int i = 0; i < lim; ++i)
                    if ((k3 >> i) & 1) k3 &= ~__shfl(r3w3, i);
            }
            if (t == 0) { skw[0] = k0; skw[1] = k1; skw[2] = k2; skw[3] = k3; }
        }
        __syncthreads();
        for (int p = t; p < V; p += 256) {
            if ((skw[p >> 6] >> (p & 63)) & 1ull) {
                int pos = atomicAdd(counter, 1);
                u32 sb = (u32)(skey64[p] >> 32);
                ckey[pos] = ((u64)sb << 32) | (u64)(u32)~(u32)(c * N + p);
                atomicAdd(&hist[(int)(sb >> 16) - HBASE], 1);
            }
        }
        return;
    }

    // ---------- safety fallback: V > 256 (not hit at these stats) ----------
    {
        int P = 512;
        while (P < V) P <<= 1;
        for (int i = V + t; i < P; i += 256) skey64[i] = 0ull;
        __syncthreads();
        for (int k = 2; k <= P; k <<= 1) {
            for (int j = k >> 1; j > 0; j >>= 1) {
                for (int i = t; i < P; i += 256) {
                    int ixj = i ^ j;
                    if (ixj > i) {
                        u64 a = skey64[i], bb = skey64[ixj];
                        bool desc = ((i & k) == 0);
                        if (desc ? (a < bb) : (a > bb)) { skey64[i] = bb; skey64[ixj] = a; }
                    }
                }
                __syncthreads();
            }
        }
        for (int p = t; p < V; p += 256) {
            int idx = (int)(~(u32)(skey64[p] & 0xffffffffu));
            float4 b = decode_box(pboxes, boxreg, idx, cl);
            sbox[p]  = b;
            sarea[p] = (b.z - b.x + 1.0f) * (b.w - b.y + 1.0f);
            skeep[p] = 1;
            cbox[c * N + p]  = b;
            corig[c * N + p] = idx;
        }
        __syncthreads();
        for (int i = 0; i < V; ++i) {
            if (skeep[i]) {
                float4 bi = sbox[i];
                float  ai = sarea[i];
                for (int j = i + 1 + t; j < V; j += 256) {
                    if (skeep[j]) {
                        float4 bj = sbox[j];
                        float lx = fmaxf(bi.x, bj.x), ly = fmaxf(bi.y, bj.y);
                        float rx = fminf(bi.z, bj.z), ry = fminf(bi.w, bj.w);
                        float ww = fmaxf(rx - lx + 1.0f, 0.0f);
                        float hh = fmaxf(ry - ly + 1.0f, 0.0f);
                        float inter = ww * hh;
                        float iou = inter / (ai + sarea[j] - inter);
                        if (iou > NMS_THRESH) skeep[j] = 0;
                    }
                }
            }
            __syncthreads();
        }
        for (int p = t; p < V; p += 256) {
            if (skeep[p]) {
                int pos = atomicAdd(counter, 1);
                u32 sb = (u32)(skey64[p] >> 32);
                ckey[pos] = ((u64)sb << 32) | (u64)(u32)~(u32)(c * N + p);
                atomicAdd(&hist[(int)(sb >> 16) - HBASE], 1);
            }
        }
    }
}

// ---------------- exact top-K via radix-select + register bitonic ----------
// Phase 1: wave-level suffix scan (integer adds — bit-exact vs the old
//          20-barrier LDS scan; same base/bstar arithmetic). 3 barriers.
// Phase 3: one-key-per-thread bitonic; j<64 phases via __shfl_xor (same
//          takeMax formula as the proven wave-64 sorter), j>=64 via LDS.
//          Keys unique => identical descending order => identical output.
__global__ __launch_bounds__(1024) void k_select(
    const int* __restrict__ counter, u64* ckey, const int* __restrict__ hist,
    float* __restrict__ sel_score, int* __restrict__ sel_flat)
{
    int t = threadIdx.x;
    int lane = t & 63, wv = t >> 6;
    __shared__ u64 keys[SELCAP];
    __shared__ int swsum[16];
    __shared__ int sb_bstar, scount;
    __shared__ u64 wk[16];
    __shared__ int wp[16];

    int M = *counter;
    if (t == 0) { sb_bstar = 0; scount = 0; }

    // phase 1: suffix scan of 1024-bucket histogram -> bucket of K-th key
    int lsum = hist[t];
    int v = lsum;
    #pragma unroll
    for (int off = 1; off < 64; off <<= 1) {
        int o = __shfl_down(v, off);
        if (lane + off < 64) v += o;
    }
    if (lane == 0) swsum[wv] = v;          // per-wave total
    __syncthreads();
    if (t < 64) {
        int w = (t < 16) ? swsum[t] : 0;
        #pragma unroll
        for (int off = 1; off < 16; off <<= 1) {
            int o = __shfl_down(w, off);
            if (t + off < 16) w += o;
        }
        if (t < 16) swsum[t] = w;          // suffix-inclusive wave totals
    }
    __syncthreads();
    int higher = (wv < 15) ? swsum[wv + 1] : 0;
    int base = v + higher - lsum;          // keys in buckets above t
    if (base < K && base + lsum >= K) sb_bstar = t;
    __syncthreads();
    int bstar = sb_bstar;

    // phase 2: compact keys with bucket >= bstar
    for (int p = t; p < M; p += 1024) {
        u64 kk = ckey[p];
        int b = (int)((kk >> 48) & 0xFFFF) - HBASE;
        if (b >= bstar) {
            int pos = atomicAdd(&scount, 1);
            if (pos < SELCAP) keys[pos] = kk;
        }
    }
    __syncthreads();
    int cnt = scount;

    if (cnt > SELCAP) {
        // exact fallback (tie flood): K rounds of argmax over dense ckey
        for (int k = 0; k < K; ++k) {
            u64 key = 0ull; int pos = -1;
            for (int p = t; p < M; p += 1024) {
                u64 kk = ckey[p];
                if (kk > key) { key = kk; pos = p; }
            }
            for (int off = 32; off; off >>= 1) {
                u64 ok2 = __shfl_down(key, off);
                int op = __shfl_down(pos, off);
                if (ok2 > key) { key = ok2; pos = op; }
            }
            if ((t & 63) == 0) { wk[t >> 6] = key; wp[t >> 6] = pos; }
            __syncthreads();
            if (t == 0) {
                for (int w = 1; w < 16; ++w)
                    if (wk[w] > key) { key = wk[w]; pos = wp[w]; }
                if (key != 0ull) {
                    sel_score[k] = __uint_as_float((u32)(key >> 32));
                    sel_flat[k]  = (int)(~(u32)(key & 0xffffffffu));
                    ckey[pos] = 0ull;
                } else { sel_score[k] = 0.0f; sel_flat[k] = 0; }
            }
            __syncthreads();
        }
        return;
    }

    // phase 3: bitonic sort padded selection, emit top K
    int P = 128;
    while (P < cnt) P <<= 1;
    for (int i = cnt + t; i < P; i += 1024) keys[i] = 0ull;
    __syncthreads();

    if (P <= 1024) {
        // register bitonic: shuffles for j<64, LDS round-trip for j>=64
        u64 key = (t < P) ? keys[t] : 0ull;
        for (int k = 2; k <= P; k <<= 1) {
            for (int j = k >> 1; j > 0; j >>= 1) {
                if (j >= 64) {
                    if (t < P) keys[t] = key;
                    __syncthreads();
                    if (t < P) {
                        u64 other = keys[t ^ j];
                        bool takeMax = (((t & j) == 0) == ((t & k) == 0));
                        bool gt = key > other;
                        key = (takeMax == gt) ? key : other;
                    }
                    __syncthreads();
                } else {
                    u64 other = __shfl_xor(key, j);
                    bool takeMax = (((t & j) == 0) == ((t & k) == 0));
                    bool gt = key > other;
                    if (t < P) key = (takeMax == gt) ? key : other;
                }
            }
        }
        if (t < K) {
            sel_score[t] = __uint_as_float((u32)(key >> 32));
            sel_flat[t]  = (int)(~(u32)(key & 0xffffffffu));
        }
        return;
    }

    // LDS bitonic fallback (P > 1024; cnt in (1024, 2048])
    for (int k = 2; k <= P; k <<= 1) {
        for (int j = k >> 1; j > 0; j >>= 1) {
            for (int i = t; i < P; i += 1024) {
                int ixj = i ^ j;
                if (ixj > i) {
                    u64 a = keys[i], b = keys[ixj];
                    bool desc = ((i & k) == 0);
                    if (desc ? (a < b) : (a > b)) { keys[i] = b; keys[ixj] = a; }
                }
            }
            __syncthreads();
        }
    }
    if (t < K) {
        u64 key = keys[t];
        sel_score[t] = __uint_as_float((u32)(key >> 32));
        sel_flat[t]  = (int)(~(u32)(key & 0xffffffffu));
    }
}

// ---------------- gather outputs ------------------------------------------
// out layout: boxes[K*4] | scores[K] | feats[K*F] | labels[K]  (all f32)
__global__ __launch_bounds__(256) void k_gather(
    const float* __restrict__ sel_score, const int* __restrict__ sel_flat,
    const int* __restrict__ corig, const float4* __restrict__ cbox,
    const float* __restrict__ feats, float* __restrict__ out)
{
    int k = blockIdx.x, t = threadIdx.x;
    float s = sel_score[k];
    bool ok = s > 0.0f;
    float4 b = make_float4(0.f, 0.f, 0.f, 0.f);
    int label = 0, orig = 0;
    if (ok) {
        int flat = sel_flat[k];        // c*N + rank
        orig  = corig[flat];
        b     = cbox[flat];
        label = (flat >> 10) + 1;      // N = 1024
    }
    if (t == 0) {
        out[k * 4 + 0] = b.x; out[k * 4 + 1] = b.y;
        out[k * 4 + 2] = b.z; out[k * 4 + 3] = b.w;
        out[K * 4 + k] = ok ? s : 0.0f;
        out[K * 4 + K + K * F + k] = (float)label;
    }
    const float4* src = (const float4*)(feats + (size_t)orig * F);
    float4* dst = (float4*)(out + K * 4 + K + (size_t)k * F);
    float4 z = make_float4(0.f, 0.f, 0.f, 0.f);
    if (t < F / 4) dst[t] = ok ? src[t] : z;
}

// ---------------------------------------------------------------------------
extern "C" void kernel_launch(void* const* d_in, const int* in_sizes, int n_in,
                              void* d_out, int out_size, void* d_ws, size_t ws_size,
                              hipStream_t stream)
{
    const float* logits = (const float*)d_in[0];   // [N,C]
    const float* boxreg = (const float*)d_in[1];   // [N,C*4]
    const float* pboxes = (const float*)d_in[2];   // [N,4]
    const float* feats  = (const float*)d_in[3];   // [N,F]
    float* out = (float*)d_out;

    char* ws = (char*)d_ws;
    size_t off = 0;
    auto alloc = [&](size_t bytes) {
        size_t cur = off;
        off = (off + bytes + 255) & ~(size_t)255;
        return cur;
    };
    u64*    ckey      = (u64*)   (ws + alloc(sizeof(u64)    * MAXC));
    float4* cbox      = (float4*)(ws + alloc(sizeof(float4) * NC1 * N));
    int*    corig     = (int*)   (ws + alloc(sizeof(int)    * NC1 * N));
    float2* ms        = (float2*)(ws + alloc(sizeof(float2) * N));
    int*    hist      = (int*)   (ws + alloc(sizeof(int)    * HSIZE));
    int*    counter   = (int*)   (ws + alloc(sizeof(int)));
    float*  sel_score = (float*) (ws + alloc(sizeof(float)  * K));
    int*    sel_flat  = (int*)   (ws + alloc(sizeof(int)    * K));

    hipLaunchKernelGGL(k_softmax, dim3(N / 4), dim3(256), 0, stream,
                       logits, ms, hist, counter);
    hipLaunchKernelGGL(k_class, dim3(NC1), dim3(256), 0, stream,
                       logits, boxreg, pboxes, ms, ckey, cbox, corig, hist, counter);
    hipLaunchKernelGGL(k_select, dim3(1), dim3(1024), 0, stream,
                       counter, ckey, hist, sel_score, sel_flat);
    hipLaunchKernelGGL(k_gather, dim3(K), dim3(256), 0, stream,
                       sel_score, sel_flat, corig, cbox, feats, out);
}